// Round 12
// baseline (561.006 us; speedup 1.0000x reference)
//
#include <hip/hip_runtime.h>
#include <math.h>

#define NPTS 1000000
#define NWORDS 31250            // NPTS/32 bitmap words
#define NKEYS 262144            // 4096 cells * 64 t-bins
#define LIST_CAP 262144
#define TWO_PI_D 6.283185307179586
#define TWO_PI_F 6.28318530717958647692f

// ---------------- f64 weight workspace (offsets in doubles) ----------------
#define OFF_W1   0        // 4352  row-major [128][34]
#define OFF_W1T  4352     // 4352  W1T[i*128+j] = W1[j*34+i]
#define OFF_W2T  8704     // 8192  W2T[j*64+k] = W2[k*128+j]
#define OFF_WS1  16896    // 128
#define OFF_BS1  17024    // 128
#define OFF_WS2T 17152    // 8192
#define OFF_BS2  25344    // 64
#define OFF_WFT  25408    // 8192  WfT[m*128+r] = Wf[r*64+m]
#define OFF_BF   33600    // 128
#define OFF_WHT  33728    // 1152  WhT[k*18+m] = Wh[m*64+k]
#define OFF_BH   34880    // 18
#define OFF_B1   34898    // 128
#define OFF_B2   35026    // 64
#define WD_DOUBLES 35090  // 280720 bytes

// ---------------- f32 / sort areas (byte offsets) ----------------
#define W2T32_OFF  280832                 // 8192 f32
#define PROJ_OFF   313600                 // 64*64*128 f32 = 2 MB
#define BMP_OFF    2410752                // 31250 u32 (area padded to 128KB)
#define CNT_OFF    2536192                // 1 u32, inside BMP pad
#define GB_OFF     2541824                // bins*128 f32 (4096 bins = 2MB)
#define HIST_OFF   4638976                // 262144 u32 = 1 MB (reused as repair list)
#define PART_OFF   5687552                // 1024 u32
#define W1XY_OFF   5691648                // 128 float2 = 1 KB
#define BFH_OFF    5692672                // 8192 short = 16 KB (B-frag hi)
#define BFL_OFF    5709056                // 8192 short = 16 KB (B-frag lo)
#define CSORT_OFF  5725440                // 1M float4 = 16 MB (16B aligned)
#define WS_SORT_MIN (CSORT_OFF + 16000000ull)

typedef __attribute__((ext_vector_type(8))) short bf16x8;
typedef __attribute__((ext_vector_type(4))) float f32x4;

__device__ __forceinline__ short f2bf(float x) {      // RNE f32->bf16 (finite)
    unsigned u = __float_as_uint(x);
    unsigned r = (u + 0x7FFFu + ((u >> 16) & 1u)) >> 16;
    return (short)r;
}
__device__ __forceinline__ float bf2f(short s) {
    return __uint_as_float(((unsigned)(unsigned short)s) << 16);
}
__device__ __forceinline__ void st4(float* d, float4 v) {
    d[0] = v.x; d[1] = v.y; d[2] = v.z; d[3] = v.w;
}

// ============================================================
// prep: f64 weights (+transposes) + f32 W2T + w1xy pack + W2 B-frags (bf16 split)
// ============================================================
__global__ __launch_bounds__(256) void prep_k(
    const float* __restrict__ W1, const float* __restrict__ b1,
    const float* __restrict__ W2, const float* __restrict__ b2,
    const float* __restrict__ Ws1, const float* __restrict__ bs1,
    const float* __restrict__ Ws2, const float* __restrict__ bs2,
    const float* __restrict__ Wf, const float* __restrict__ bf,
    const float* __restrict__ Wh, const float* __restrict__ bh,
    char* __restrict__ ws)
{
    double* wd = (double*)ws;
    float* w2t32 = (float*)(ws + W2T32_OFF);
    float2* w1xyp = (float2*)(ws + W1XY_OFF);
    short* bfh = (short*)(ws + BFH_OFF);
    short* bfl = (short*)(ws + BFL_OFF);
    int i = blockIdx.x * 256 + threadIdx.x;
    if (i < 4352) {
        wd[OFF_W1 + i] = (double)W1[i];
        int row = i >> 7, col = i & 127;           // W1T[row*128+col]
        wd[OFF_W1T + i] = (double)W1[col * 34 + row];
    }
    if (i < 8192) {
        int j = i >> 6, k = i & 63;
        float w2v = W2[k * 128 + j];
        wd[OFF_W2T + i] = (double)w2v;  w2t32[i] = w2v;
        wd[OFF_WS2T + i] = (double)Ws2[k * 128 + j];
        int m = i >> 7, r = i & 127;
        wd[OFF_WFT + i] = (double)Wf[r * 64 + m];
    }
    if (i < 8192) {   // MFMA B-fragments of W2: B[j][n] = W2[n*128+j], bf16 hi/lo
        int jj = i & 7, l = (i >> 3) & 63, f = i >> 9;
        int ks = f >> 2, nt = f & 3;
        int j = ks * 32 + ((l >> 4) << 3) + jj;
        int nn = nt * 16 + (l & 15);
        float v = W2[nn * 128 + j];
        short hi = f2bf(v);
        bfh[i] = hi;
        bfl[i] = f2bf(v - bf2f(hi));
    }
    if (i < 1152) {
        int m = i % 18, k = i / 18;
        wd[OFF_WHT + i] = (double)Wh[m * 64 + k];
    }
    if (i < 128) {
        wd[OFF_WS1 + i] = (double)Ws1[i];
        wd[OFF_BS1 + i] = (double)bs1[i];
        wd[OFF_BF  + i] = (double)bf[i];
        wd[OFF_B1  + i] = (double)b1[i];
        w1xyp[i] = make_float2(W1[i * 34], W1[i * 34 + 1]);
    }
    if (i < 64) {
        wd[OFF_BS2 + i] = (double)bs2[i];
        wd[OFF_B2  + i] = (double)b2[i];
    }
    if (i < 18) wd[OFF_BH + i] = (double)bh[i];
}

// ============================================================
// proj table + zero bitmap / hist / counter
// ============================================================
__global__ __launch_bounds__(256) void build_proj(
    const float* __restrict__ grid, const double* __restrict__ wd,
    float* __restrict__ proj, unsigned* __restrict__ bmp,
    unsigned* __restrict__ hist, unsigned* __restrict__ cnt)
{
    int idx = blockIdx.x * 256 + threadIdx.x;
    if (idx < NWORDS) bmp[idx] = 0u;
    if (hist && idx < NKEYS) hist[idx] = 0u;
    if (idx == 0) *cnt = 0u;
    if (idx >= 64 * 64 * 128) return;
    int j = idx & 127, node = idx >> 7;
    const double* W1T = wd + OFF_W1T;
    const float* g = grid + node * 32;
    double s0 = 0, s1 = 0, s2 = 0, s3 = 0;
#pragma unroll
    for (int i = 0; i < 32; i += 4) {
        s0 = fma((double)g[i + 0], W1T[(2 + i + 0) * 128 + j], s0);
        s1 = fma((double)g[i + 1], W1T[(2 + i + 1) * 128 + j], s1);
        s2 = fma((double)g[i + 2], W1T[(2 + i + 2) * 128 + j], s2);
        s3 = fma((double)g[i + 3], W1T[(2 + i + 3) * 128 + j], s3);
    }
    proj[idx] = (float)((s0 + s2) + (s1 + s3));
}

// ============================================================
// gamma/beta t-table (f64 math), one wave per bin
// ============================================================
__global__ __launch_bounds__(256) void build_gb(
    const double* __restrict__ wd, float* __restrict__ GB, int bins)
{
    __shared__ double sh[4 * 128];
    int wid = threadIdx.x >> 6, lane = threadIdx.x & 63;
    double* buf = sh + wid * 128;
    int bin = blockIdx.x * 4 + wid;
    if (bin >= bins) return;
    double t = -1.0 + 2.0 * (double)bin / (double)(bins - 1);

    buf[lane]      = sin(30.0 * fma(t, wd[OFF_WS1 + lane],      wd[OFF_BS1 + lane]));
    buf[lane + 64] = sin(30.0 * fma(t, wd[OFF_WS1 + 64 + lane], wd[OFF_BS1 + 64 + lane]));
    __threadfence_block();
    double a0 = wd[OFF_BS2 + lane], a1 = 0, a2 = 0, a3 = 0;
    const double* W = wd + OFF_WS2T;
#pragma unroll 2
    for (int j = 0; j < 128; j += 4) {
        a0 = fma(buf[j + 0], W[(j + 0) * 64 + lane], a0);
        a1 = fma(buf[j + 1], W[(j + 1) * 64 + lane], a1);
        a2 = fma(buf[j + 2], W[(j + 2) * 64 + lane], a2);
        a3 = fma(buf[j + 3], W[(j + 3) * 64 + lane], a3);
    }
    double ht = sin((a0 + a2) + (a1 + a3));
    __threadfence_block();
    buf[lane] = ht;
    __threadfence_block();
    double g0 = wd[OFF_BF + lane], g1 = 0, e0 = wd[OFF_BF + 64 + lane], e1 = 0;
    const double* WT = wd + OFF_WFT;
#pragma unroll 2
    for (int m = 0; m < 64; m += 2) {
        double h0 = buf[m], h1 = buf[m + 1];
        g0 = fma(h0, WT[(m + 0) * 128 + lane], g0);
        g1 = fma(h1, WT[(m + 1) * 128 + lane], g1);
        e0 = fma(h0, WT[(m + 0) * 128 + 64 + lane], e0);
        e1 = fma(h1, WT[(m + 1) * 128 + 64 + lane], e1);
    }
    GB[(size_t)bin * 128 + lane]      = (float)fma(0.1, tanh(g0 + g1), 1.0);
    GB[(size_t)bin * 128 + 64 + lane] = (float)tanh(e0 + e1);
}

// ============================================================
// sort machinery: key = (cell<<6) | tbin
// ============================================================
__device__ __forceinline__ unsigned point_key(float xf, float yf, float tf)
{
    float xi = (xf + 1.0f) * 0.5f * 63.0f;
    float yi = (yf + 1.0f) * 0.5f * 63.0f;
    int x0 = (int)floorf(xi); x0 = x0 < 0 ? 0 : (x0 > 62 ? 62 : x0);
    int y0 = (int)floorf(yi); y0 = y0 < 0 ? 0 : (y0 > 62 ? 62 : y0);
    float u = (tf + 1.0f) * 32.0f;
    int tb = (int)u; tb = tb < 0 ? 0 : (tb > 63 ? 63 : tb);
    return ((unsigned)(y0 * 64 + x0) << 6) | (unsigned)tb;
}

__global__ __launch_bounds__(256) void hist_k(
    const float* __restrict__ coords, unsigned* __restrict__ hist)
{
    int n = blockIdx.x * 256 + threadIdx.x;
    if (n >= NPTS) return;
    unsigned key = point_key(coords[3 * n], coords[3 * n + 1], coords[3 * n + 2]);
    atomicAdd(&hist[key], 1u);
}

__global__ __launch_bounds__(256) void scan1_k(
    const unsigned* __restrict__ hist, unsigned* __restrict__ part)
{
    __shared__ unsigned s[256];
    int t = threadIdx.x;
    s[t] = hist[blockIdx.x * 256 + t];
    __syncthreads();
    for (int off = 128; off > 0; off >>= 1) {
        if (t < off) s[t] += s[t + off];
        __syncthreads();
    }
    if (t == 0) part[blockIdx.x] = s[0];
}

__global__ __launch_bounds__(1024) void scan2_k(unsigned* __restrict__ part)
{
    __shared__ unsigned s[1024];
    int t = threadIdx.x;
    unsigned orig = part[t];
    s[t] = orig;
    __syncthreads();
    for (int off = 1; off < 1024; off <<= 1) {
        unsigned tmp = (t >= off) ? s[t - off] : 0u;
        __syncthreads();
        s[t] += tmp;
        __syncthreads();
    }
    part[t] = s[t] - orig;        // exclusive prefix
}

__global__ __launch_bounds__(256) void scan3_k(
    unsigned* __restrict__ hist, const unsigned* __restrict__ part)
{
    __shared__ unsigned s[256];
    int t = threadIdx.x;
    int i = blockIdx.x * 256 + t;
    unsigned orig = hist[i];
    s[t] = orig;
    __syncthreads();
    for (int off = 1; off < 256; off <<= 1) {
        unsigned tmp = (t >= off) ? s[t - off] : 0u;
        __syncthreads();
        s[t] += tmp;
        __syncthreads();
    }
    hist[i] = s[t] - orig + part[blockIdx.x];   // global exclusive offset
}

__global__ __launch_bounds__(256) void scatter_k(
    const float* __restrict__ coords, unsigned* __restrict__ offs,
    float4* __restrict__ csort)
{
    int n = blockIdx.x * 256 + threadIdx.x;
    if (n >= NPTS) return;
    float xf = coords[3 * n], yf = coords[3 * n + 1], tf = coords[3 * n + 2];
    unsigned key = point_key(xf, yf, tf);
    unsigned pos = atomicAdd(&offs[key], 1u);
    csort[pos] = make_float4(xf, yf, tf, __int_as_float(n));
}

// ============================================================
// exact f64 wave-cooperative FULL point eval (overflow repair + fallback)
// (single-wave blocks: buf is the block's private LDS)
// ============================================================
__device__ __forceinline__ void eval_pt_wave(
    int n, int lane, double* buf,
    const float* __restrict__ coords, const float* __restrict__ grid,
    const double* __restrict__ wd, float* __restrict__ out, bool wrc)
{
    const float xf = coords[3 * n + 0];
    const float yf = coords[3 * n + 1];
    const float tf = coords[3 * n + 2];

    double xi = ((double)xf + 1.0) * 0.5 * 63.0;
    double yi = ((double)yf + 1.0) * 0.5 * 63.0;
    int x0 = (int)floor(xi); x0 = x0 < 0 ? 0 : (x0 > 62 ? 62 : x0);
    int y0 = (int)floor(yi); y0 = y0 < 0 ? 0 : (y0 > 62 ? 62 : y0);
    double dx = xi - (double)x0;
    double dy = yi - (double)y0;
    double w00 = (1.0 - dx) * (1.0 - dy);
    double w01 = (1.0 - dx) * dy;
    double w10 = dx * (1.0 - dy);
    double w11 = dx * dy;
    const float* f00 = grid + ((size_t)(y0 * 64 + x0)) * 32;

    if (lane < 32) {
        double v = (w00 * (double)f00[lane] + w01 * (double)f00[2048 + lane])
                 + (w10 * (double)f00[32 + lane] + w11 * (double)f00[2080 + lane]);
        buf[192 + 2 + lane] = v;
    } else if (lane == 32) buf[192 + 0] = (double)xf;
    else if (lane == 33)   buf[192 + 1] = (double)yf;
    __threadfence_block();

    double hlo = wd[OFF_B1 + lane], hhi = wd[OFF_B1 + 64 + lane];
    {
        const double* W = wd + OFF_W1T;
#pragma unroll 2
        for (int i = 0; i < 34; ++i) {
            double xv = buf[192 + i];
            hlo = fma(xv, W[i * 128 + lane], hlo);
            hhi = fma(xv, W[i * 128 + 64 + lane], hhi);
        }
    }
    buf[lane]      = fmax(hlo, 0.0);
    buf[64 + lane] = fmax(hhi, 0.0);
    __threadfence_block();

    double c0 = wd[OFF_B2 + lane], c1 = 0, c2 = 0, c3 = 0;
    {
        const double* W = wd + OFF_W2T;
#pragma unroll 2
        for (int j = 0; j < 128; j += 4) {
            c0 = fma(buf[j + 0], W[(j + 0) * 64 + lane], c0);
            c1 = fma(buf[j + 1], W[(j + 1) * 64 + lane], c1);
            c2 = fma(buf[j + 2], W[(j + 2) * 64 + lane], c2);
            c3 = fma(buf[j + 3], W[(j + 3) * 64 + lane], c3);
        }
    }
    double hxy = fmax((c0 + c2) + (c1 + c3), 0.0);
    __threadfence_block();

    double tt = (double)tf;
    buf[lane]      = sin(30.0 * fma(tt, wd[OFF_WS1 + lane],      wd[OFF_BS1 + lane]));
    buf[64 + lane] = sin(30.0 * fma(tt, wd[OFF_WS1 + 64 + lane], wd[OFF_BS1 + 64 + lane]));
    __threadfence_block();
    double a0 = wd[OFF_BS2 + lane], a1 = 0, a2 = 0, a3 = 0;
    {
        const double* W = wd + OFF_WS2T;
#pragma unroll 2
        for (int j = 0; j < 128; j += 4) {
            a0 = fma(buf[j + 0], W[(j + 0) * 64 + lane], a0);
            a1 = fma(buf[j + 1], W[(j + 1) * 64 + lane], a1);
            a2 = fma(buf[j + 2], W[(j + 2) * 64 + lane], a2);
            a3 = fma(buf[j + 3], W[(j + 3) * 64 + lane], a3);
        }
    }
    buf[128 + lane] = sin((a0 + a2) + (a1 + a3));
    __threadfence_block();

    double g0 = wd[OFF_BF + lane], g1 = 0, e0 = wd[OFF_BF + 64 + lane], e1 = 0;
    {
        const double* W = wd + OFF_WFT;
#pragma unroll 2
        for (int m = 0; m < 64; m += 2) {
            double h0 = buf[128 + m], h1 = buf[128 + m + 1];
            g0 = fma(h0, W[(m + 0) * 128 + lane], g0);
            g1 = fma(h1, W[(m + 1) * 128 + lane], g1);
            e0 = fma(h0, W[(m + 0) * 128 + 64 + lane], e0);
            e1 = fma(h1, W[(m + 1) * 128 + 64 + lane], e1);
        }
    }
    double fused = fma(fma(0.1, tanh(g0 + g1), 1.0), hxy, tanh(e0 + e1));
    __threadfence_block();
    buf[lane] = fused;
    __threadfence_block();

    if (lane < 18) {
        const double* W = wd + OFF_WHT;
        double p0 = wd[OFF_BH + lane], p1 = 0;
#pragma unroll 2
        for (int k = 0; k < 64; k += 2) {
            p0 = fma(buf[k + 0], W[(k + 0) * 18 + lane], p0);
            p1 = fma(buf[k + 1], W[(k + 1) * 18 + lane], p1);
        }
        buf[128 + lane] = p0 + p1;
    }
    __threadfence_block();

    if (lane < 18) {
        int m6 = lane % 6;
        double p = buf[128 + lane];
        float ov;
        if (m6 == 0) {
            double l0 = buf[128 + 0], l1 = buf[128 + 6], l2 = buf[128 + 12];
            double mx = fmax(l0, fmax(l1, l2));
            double s = exp(l0 - mx) + exp(l1 - mx) + exp(l2 - mx);
            ov = (float)(exp(p - mx) / s);
        } else if (m6 == 1) ov = (float)fmax(p, 0.0);
        else if (m6 == 2)   ov = (float)(p - floor(p / TWO_PI_D) * TWO_PI_D);
        else if (m6 == 5)   ov = (float)(0.99 * tanh(p));
        else { double v = fmin(fmax(p, -10.0), 10.0); ov = (float)exp(v); }
        out[(size_t)n * 18 + lane] = ov;
    }
    if (wrc && lane < 3)
        out[(size_t)18 * NPTS + (size_t)n * 3 + lane] = coords[3 * n + lane];
    __threadfence_block();
}

// ============================================================
// exact f64 ANGLE-ONLY eval: repairs out[n*18 + {2,8,14}] only
// ============================================================
__device__ __forceinline__ void eval_angle_wave(
    int n, int lane, double* buf,
    const float* __restrict__ coords, const float* __restrict__ grid,
    const double* __restrict__ wd, const float* __restrict__ Wh,
    const float* __restrict__ bh, float* __restrict__ out)
{
    const float xf = coords[3 * n + 0];
    const float yf = coords[3 * n + 1];
    const float tf = coords[3 * n + 2];

    double xi = ((double)xf + 1.0) * 0.5 * 63.0;
    double yi = ((double)yf + 1.0) * 0.5 * 63.0;
    int x0 = (int)floor(xi); x0 = x0 < 0 ? 0 : (x0 > 62 ? 62 : x0);
    int y0 = (int)floor(yi); y0 = y0 < 0 ? 0 : (y0 > 62 ? 62 : y0);
    double dx = xi - (double)x0;
    double dy = yi - (double)y0;
    double w00 = (1.0 - dx) * (1.0 - dy);
    double w01 = (1.0 - dx) * dy;
    double w10 = dx * (1.0 - dy);
    double w11 = dx * dy;
    const float* f00 = grid + ((size_t)(y0 * 64 + x0)) * 32;

    if (lane < 32) {
        double v = (w00 * (double)f00[lane] + w01 * (double)f00[2048 + lane])
                 + (w10 * (double)f00[32 + lane] + w11 * (double)f00[2080 + lane]);
        buf[192 + 2 + lane] = v;
    } else if (lane == 32) buf[192 + 0] = (double)xf;
    else if (lane == 33)   buf[192 + 1] = (double)yf;
    __threadfence_block();

    double hlo = wd[OFF_B1 + lane], hhi = wd[OFF_B1 + 64 + lane];
    {
        const double* W = wd + OFF_W1T;
#pragma unroll 2
        for (int i = 0; i < 34; ++i) {
            double xv = buf[192 + i];
            hlo = fma(xv, W[i * 128 + lane], hlo);
            hhi = fma(xv, W[i * 128 + 64 + lane], hhi);
        }
    }
    buf[lane]      = fmax(hlo, 0.0);
    buf[64 + lane] = fmax(hhi, 0.0);
    __threadfence_block();

    double c0 = wd[OFF_B2 + lane], c1 = 0, c2 = 0, c3 = 0;
    {
        const double* W = wd + OFF_W2T;
#pragma unroll 2
        for (int j = 0; j < 128; j += 4) {
            c0 = fma(buf[j + 0], W[(j + 0) * 64 + lane], c0);
            c1 = fma(buf[j + 1], W[(j + 1) * 64 + lane], c1);
            c2 = fma(buf[j + 2], W[(j + 2) * 64 + lane], c2);
            c3 = fma(buf[j + 3], W[(j + 3) * 64 + lane], c3);
        }
    }
    double hxy = fmax((c0 + c2) + (c1 + c3), 0.0);
    __threadfence_block();

    double tt = (double)tf;
    buf[lane]      = sin(30.0 * fma(tt, wd[OFF_WS1 + lane],      wd[OFF_BS1 + lane]));
    buf[64 + lane] = sin(30.0 * fma(tt, wd[OFF_WS1 + 64 + lane], wd[OFF_BS1 + 64 + lane]));
    __threadfence_block();
    double a0 = wd[OFF_BS2 + lane], a1 = 0, a2 = 0, a3 = 0;
    {
        const double* W = wd + OFF_WS2T;
#pragma unroll 2
        for (int j = 0; j < 128; j += 4) {
            a0 = fma(buf[j + 0], W[(j + 0) * 64 + lane], a0);
            a1 = fma(buf[j + 1], W[(j + 1) * 64 + lane], a1);
            a2 = fma(buf[j + 2], W[(j + 2) * 64 + lane], a2);
            a3 = fma(buf[j + 3], W[(j + 3) * 64 + lane], a3);
        }
    }
    buf[128 + lane] = sin((a0 + a2) + (a1 + a3));
    __threadfence_block();

    double g0 = wd[OFF_BF + lane], g1 = 0, e0 = wd[OFF_BF + 64 + lane], e1 = 0;
    {
        const double* W = wd + OFF_WFT;
#pragma unroll 2
        for (int m = 0; m < 64; m += 2) {
            double h0 = buf[128 + m], h1 = buf[128 + m + 1];
            g0 = fma(h0, W[(m + 0) * 128 + lane], g0);
            g1 = fma(h1, W[(m + 1) * 128 + lane], g1);
            e0 = fma(h0, W[(m + 0) * 128 + 64 + lane], e0);
            e1 = fma(h1, W[(m + 1) * 128 + 64 + lane], e1);
        }
    }
    double fused = fma(fma(0.1, tanh(g0 + g1), 1.0), hxy, tanh(e0 + e1));

    // head rows 2, 8, 14 only: per-lane product + butterfly reduce (f64 exact)
    double p2  = fused * (double)Wh[2 * 64 + lane];
    double p8  = fused * (double)Wh[8 * 64 + lane];
    double p14 = fused * (double)Wh[14 * 64 + lane];
#pragma unroll
    for (int off = 32; off > 0; off >>= 1) {
        p2  += __shfl_xor(p2, off);
        p8  += __shfl_xor(p8, off);
        p14 += __shfl_xor(p14, off);
    }
    if (lane == 0) {
        double q2  = p2  + (double)bh[2];
        double q8  = p8  + (double)bh[8];
        double q14 = p14 + (double)bh[14];
        out[(size_t)n * 18 + 2]  = (float)(q2  - floor(q2  / TWO_PI_D) * TWO_PI_D);
        out[(size_t)n * 18 + 8]  = (float)(q8  - floor(q8  / TWO_PI_D) * TWO_PI_D);
        out[(size_t)n * 18 + 14] = (float)(q14 - floor(q14 / TWO_PI_D) * TWO_PI_D);
    }
    __threadfence_block();
}

// ============================================================
// repair: load-balanced list walk, 1-wave blocks (angle-only)
// ============================================================
__global__ __launch_bounds__(64) void repair_list(
    const float* __restrict__ coords, const float* __restrict__ grid,
    const double* __restrict__ wd, const float* __restrict__ Wh,
    const float* __restrict__ bh, const unsigned* __restrict__ cnt,
    const unsigned* __restrict__ list, float* __restrict__ out)
{
    __shared__ double buf[232];
    int lane = threadIdx.x;
    unsigned total = *cnt;
    if (total > LIST_CAP) total = LIST_CAP;
    for (unsigned i = blockIdx.x; i < total; i += gridDim.x)
        eval_angle_wave((int)list[i], lane, buf, coords, grid, wd, Wh, bh, out);
}

// overflow / fallback: bitmap scan, full eval, 1-wave blocks
__global__ __launch_bounds__(64) void repair_bmp(
    const float* __restrict__ coords, const float* __restrict__ grid,
    const double* __restrict__ wd, const unsigned* __restrict__ bmp,
    float* __restrict__ out)
{
    __shared__ double buf[232];
    int lane = threadIdx.x;
    for (unsigned w = blockIdx.x; w < NWORDS; w += gridDim.x) {
        unsigned word = bmp[w];
        while (word) {
            unsigned b = (unsigned)__builtin_ctz(word);
            word &= word - 1;
            eval_pt_wave((int)(w * 32 + b), lane, buf, coords, grid, wd, out, false);
        }
    }
}

__global__ __launch_bounds__(64) void full_f64_fb(
    const float* __restrict__ coords, const float* __restrict__ grid,
    const double* __restrict__ wd, float* __restrict__ out)
{
    __shared__ double buf[232];
    int lane = threadIdx.x;
    for (unsigned n = blockIdx.x; n < NPTS; n += gridDim.x)
        eval_pt_wave((int)n, lane, buf, coords, grid, wd, out, true);
}

// ============================================================
// MFMA main: 1 wave = 1 block = 64 sorted points
// ks loop at unroll 2: compiler software-pipelines loads of ks+1
// under compute of ks (only change vs R11 baseline).
// ============================================================
__global__ __launch_bounds__(64) void main_mfma(
    const float4* __restrict__ csort,
    const float* __restrict__ proj, const float* __restrict__ GB,
    const short* __restrict__ bfH, const short* __restrict__ bfL,
    const float* __restrict__ w1xy, const float* __restrict__ b1,
    const float* __restrict__ b2,
    const float* __restrict__ Wh, const float* __restrict__ bh,
    int bins, float tau, float* __restrict__ out,
    unsigned* __restrict__ cnt, unsigned* __restrict__ list,
    unsigned* __restrict__ bmp)
{
    __shared__ float wl[2048];          // 8 KB, private to this single-wave block
    const int lane = threadIdx.x;
    const int wavebase = blockIdx.x * 64;

    f32x4 acc[4][4];
#pragma unroll
    for (int a = 0; a < 4; ++a)
#pragma unroll
        for (int b = 0; b < 4; ++b) acc[a][b] = (f32x4){0.f, 0.f, 0.f, 0.f};

    // per-thread point + bilinear params
    float4 myc = csort[wavebase + lane];
    float w00, w01, w10, w11; int node;
    {
        float xi = (myc.x + 1.0f) * 0.5f * 63.0f;
        float yi = (myc.y + 1.0f) * 0.5f * 63.0f;
        int x0 = (int)floorf(xi); x0 = x0 < 0 ? 0 : (x0 > 62 ? 62 : x0);
        int y0 = (int)floorf(yi); y0 = y0 < 0 ? 0 : (y0 > 62 ? 62 : y0);
        float dx = xi - (float)x0;
        float dy = yi - (float)y0;
        w00 = (1.0f - dx) * (1.0f - dy);
        w01 = (1.0f - dx) * dy;
        w10 = dx * (1.0f - dy);
        w11 = dx * dy;
        node = y0 * 64 + x0;
    }
    // distribute tile-row params via shuffles (A-frag row = lane&15 of tile mt)
    float px[4], py[4], pw00[4], pw01[4], pw10[4], pw11[4];
    int pnode[4];
#pragma unroll
    for (int mt = 0; mt < 4; ++mt) {
        int src = mt * 16 + (lane & 15);
        px[mt]   = __shfl(myc.x, src);
        py[mt]   = __shfl(myc.y, src);
        pw00[mt] = __shfl(w00, src);
        pw01[mt] = __shfl(w01, src);
        pw10[mt] = __shfl(w10, src);
        pw11[mt] = __shfl(w11, src);
        pnode[mt] = __shfl(node, src);
    }

#pragma unroll 2
    for (int ks = 0; ks < 4; ++ks) {
        const int dbase = ks * 32 + ((lane >> 4) << 3);
        bf16x8 bHf[4], bLf[4];
#pragma unroll
        for (int nt = 0; nt < 4; ++nt) {
            int fi = ((ks * 4 + nt) * 64 + lane) * 8;
            bHf[nt] = *(const bf16x8*)(bfH + fi);
            bLf[nt] = *(const bf16x8*)(bfL + fi);
        }
        float b1r[8];
        st4(b1r,     *(const float4*)(b1 + dbase));
        st4(b1r + 4, *(const float4*)(b1 + dbase + 4));
        float wvr[16];                         // (x,y) pairs for 8 dims
        {
            const float4* wxy = (const float4*)w1xy + (dbase >> 1);
            st4(wvr,      wxy[0]);
            st4(wvr + 4,  wxy[1]);
            st4(wvr + 8,  wxy[2]);
            st4(wvr + 12, wxy[3]);
        }
#pragma unroll
        for (int mt = 0; mt < 4; ++mt) {
            const float* pj = proj + pnode[mt] * 128 + dbase;
            float q00[8], q10[8], q01[8], q11[8];
            st4(q00,     *(const float4*)(pj));
            st4(q00 + 4, *(const float4*)(pj + 4));
            st4(q10,     *(const float4*)(pj + 128));
            st4(q10 + 4, *(const float4*)(pj + 132));
            st4(q01,     *(const float4*)(pj + 8192));
            st4(q01 + 4, *(const float4*)(pj + 8196));
            st4(q11,     *(const float4*)(pj + 8320));
            st4(q11 + 4, *(const float4*)(pj + 8324));
            bf16x8 ah, al;
            float xx = px[mt], yy = py[mt];
            float a00 = pw00[mt], a01 = pw01[mt], a10 = pw10[mt], a11 = pw11[mt];
#pragma unroll
            for (int jj = 0; jj < 8; ++jj) {
                float h = b1r[jj];
                h = fmaf(xx, wvr[jj * 2], h);
                h = fmaf(yy, wvr[jj * 2 + 1], h);
                h = fmaf(a00, q00[jj], h);
                h = fmaf(a01, q01[jj], h);
                h = fmaf(a10, q10[jj], h);
                h = fmaf(a11, q11[jj], h);
                h = fmaxf(h, 0.0f);
                short hi = f2bf(h);
                ah[jj] = hi;
                al[jj] = f2bf(h - bf2f(hi));
            }
#pragma unroll
            for (int nt = 0; nt < 4; ++nt) {
                acc[mt][nt] = __builtin_amdgcn_mfma_f32_16x16x32_bf16(ah, bHf[nt], acc[mt][nt], 0, 0, 0);
                acc[mt][nt] = __builtin_amdgcn_mfma_f32_16x16x32_bf16(ah, bLf[nt], acc[mt][nt], 0, 0, 0);
                acc[mt][nt] = __builtin_amdgcn_mfma_f32_16x16x32_bf16(al, bHf[nt], acc[mt][nt], 0, 0, 0);
            }
        }
    }

    // ---- phase 2: LDS transpose (swizzled) + FiLM + head, thread = point ----
    float pp[18];
    int ib, n_out;
    float ft;
    {
        float u = (myc.z + 1.0f) * 0.5f * (float)(bins - 1);
        ib = (int)u; ib = ib < 0 ? 0 : (ib > bins - 2 ? bins - 2 : ib);
        ft = u - (float)ib;
        n_out = __float_as_int(myc.w);
#pragma unroll
        for (int m = 0; m < 18; ++m) pp[m] = bh[m];
    }
    const int rbase = ((lane >> 4) << 2);
#pragma unroll
    for (int half = 0; half < 2; ++half) {
#pragma unroll
        for (int nt2 = 0; nt2 < 2; ++nt2) {
            int nt = half * 2 + nt2;
            int kl = nt2 * 16 + (lane & 15);
#pragma unroll
            for (int mt = 0; mt < 4; ++mt)
#pragma unroll
                for (int r = 0; r < 4; ++r) {
                    int pt = mt * 16 + rbase + r;
                    wl[kl * 64 + ((pt + kl) & 63)] = acc[mt][nt][r];
                }
        }
        __syncthreads();
        {
            const float* GAg = GB + (size_t)ib * 128 + half * 32;
            const float* GAe = GAg + 64;
            const float* GBg = GB + (size_t)(ib + 1) * 128 + half * 32;
            const float* GBe = GBg + 64;
#pragma unroll
            for (int c = 0; c < 8; ++c) {
                float g0r[4], g1r[4], e0r[4], e1r[4];
                st4(g0r, *(const float4*)(GAg + c * 4));
                st4(g1r, *(const float4*)(GBg + c * 4));
                st4(e0r, *(const float4*)(GAe + c * 4));
                st4(e1r, *(const float4*)(GBe + c * 4));
#pragma unroll
                for (int q = 0; q < 4; ++q) {
                    int kl = c * 4 + q, k = half * 32 + kl;
                    float v = wl[kl * 64 + ((lane + kl) & 63)];
                    float a = fmaxf(v + b2[k], 0.0f);
                    float ga = fmaf(ft, g1r[q] - g0r[q], g0r[q]);
                    float be = fmaf(ft, e1r[q] - e0r[q], e0r[q]);
                    float fz = fmaf(ga, a, be);
#pragma unroll
                    for (int m = 0; m < 18; ++m)
                        pp[m] = fmaf(fz, Wh[m * 64 + k], pp[m]);
                }
            }
        }
        __syncthreads();
    }

    float o[18];
    bool flag = false;
    {
        float l0 = pp[0], l1 = pp[6], l2 = pp[12];
        float mx = fmaxf(l0, fmaxf(l1, l2));
        float ex0 = __expf(l0 - mx), ex1 = __expf(l1 - mx), ex2 = __expf(l2 - mx);
        float inv = __fdividef(1.0f, ex0 + ex1 + ex2);
        o[0] = ex0 * inv; o[6] = ex1 * inv; o[12] = ex2 * inv;
#pragma unroll
        for (int kk = 0; kk < 3; ++kk) {
            o[kk * 6 + 1] = fmaxf(pp[kk * 6 + 1], 0.0f);
            float an = pp[kk * 6 + 2];
            float fl = floorf(an * (1.0f / TWO_PI_F));
            o[kk * 6 + 2] = an - fl * TWO_PI_F;
            float r = an - TWO_PI_F * rintf(an * (1.0f / TWO_PI_F));
            if (fabsf(r) < tau) flag = true;
            float v1 = fminf(fmaxf(pp[kk * 6 + 3], -10.0f), 10.0f);
            o[kk * 6 + 3] = __expf(v1);
            float v2 = fminf(fmaxf(pp[kk * 6 + 4], -10.0f), 10.0f);
            o[kk * 6 + 4] = __expf(v2);
            float e2 = __expf(2.0f * pp[kk * 6 + 5]);
            o[kk * 6 + 5] = 0.99f * __fdividef(e2 - 1.0f, e2 + 1.0f);
        }
    }

    float* og = out + (size_t)n_out * 18;
#pragma unroll
    for (int i = 0; i < 18; i += 2)
        *reinterpret_cast<float2*>(og + i) = make_float2(o[i], o[i + 1]);
    float* oc = out + (size_t)18 * NPTS + (size_t)n_out * 3;
    oc[0] = myc.x; oc[1] = myc.y; oc[2] = myc.z;

    if (flag) {
        unsigned idx = atomicAdd(cnt, 1u);
        if (idx < LIST_CAP) list[idx] = (unsigned)n_out;
        else atomicOr(&bmp[n_out >> 5], 1u << (n_out & 31));
    }
}

// ============================================================
// fast f32 point body (fallback unsorted main only; bitmap flags)
// ============================================================
__global__ __launch_bounds__(256) void main_unsorted(
    const float* __restrict__ coords,
    const float* __restrict__ W1, const float* __restrict__ b1,
    const float* __restrict__ b2,
    const float* __restrict__ Wh, const float* __restrict__ bh,
    const float* __restrict__ W2T,
    const float* __restrict__ PROJ, const float* __restrict__ GB,
    int bins, float tau,
    float* __restrict__ out, unsigned* __restrict__ bmp)
{
    int n = blockIdx.x * 256 + threadIdx.x;
    if (n >= NPTS) return;
    float xf = coords[3 * n], yf = coords[3 * n + 1], tf = coords[3 * n + 2];

    float xi = (xf + 1.0f) * 0.5f * 63.0f;
    float yi = (yf + 1.0f) * 0.5f * 63.0f;
    int x0 = (int)floorf(xi); x0 = x0 < 0 ? 0 : (x0 > 62 ? 62 : x0);
    int y0 = (int)floorf(yi); y0 = y0 < 0 ? 0 : (y0 > 62 ? 62 : y0);
    float dx = xi - (float)x0;
    float dy = yi - (float)y0;
    float w00 = (1.0f - dx) * (1.0f - dy);
    float w01 = (1.0f - dx) * dy;
    float w10 = dx * (1.0f - dy);
    float w11 = dx * dy;
    int node = y0 * 64 + x0;

    float u = (tf + 1.0f) * 0.5f * (float)(bins - 1);
    int ib = (int)u; ib = ib < 0 ? 0 : (ib > bins - 2 ? bins - 2 : ib);
    float ft = u - (float)ib;

    const float4* P00 = (const float4*)(PROJ + (size_t)node * 128);
    const float4* P10 = P00 + 32;
    const float4* P01 = P00 + 2048;
    const float4* P11 = P01 + 32;

    float acc[64];
#pragma unroll
    for (int k = 0; k < 64; ++k) acc[k] = b2[k];

#pragma unroll 1
    for (int jb = 0; jb < 32; ++jb) {
        float4 a00 = P00[jb], a01 = P01[jb], a10 = P10[jb], a11 = P11[jb];
        const float* a00f = (const float*)&a00;
        const float* a01f = (const float*)&a01;
        const float* a10f = (const float*)&a10;
        const float* a11f = (const float*)&a11;
        const float* w1b = W1 + jb * 136;
#pragma unroll
        for (int q = 0; q < 4; ++q) {
            float hq = b1[jb * 4 + q];
            hq = fmaf(xf, w1b[q * 34 + 0], hq);
            hq = fmaf(yf, w1b[q * 34 + 1], hq);
            hq = fmaf(w00, a00f[q], hq);
            hq = fmaf(w01, a01f[q], hq);
            hq = fmaf(w10, a10f[q], hq);
            hq = fmaf(w11, a11f[q], hq);
            hq = fmaxf(hq, 0.0f);
            const float* w2c = W2T + (jb * 4 + q) * 64;
#pragma unroll
            for (int k = 0; k < 64; ++k) acc[k] = fmaf(hq, w2c[k], acc[k]);
        }
    }
#pragma unroll
    for (int k = 0; k < 64; ++k) acc[k] = fmaxf(acc[k], 0.0f);

    float pp[18];
#pragma unroll
    for (int m = 0; m < 18; ++m) pp[m] = bh[m];

    const float4* GA = (const float4*)(GB + (size_t)ib * 128);
    const float4* GBn = (const float4*)(GB + (size_t)(ib + 1) * 128);
#pragma unroll
    for (int kb = 0; kb < 16; ++kb) {
        float4 g0 = GA[kb], g1 = GBn[kb], e0 = GA[16 + kb], e1 = GBn[16 + kb];
        const float* g0f = (const float*)&g0;
        const float* g1f = (const float*)&g1;
        const float* e0f = (const float*)&e0;
        const float* e1f = (const float*)&e1;
        float fz[4];
#pragma unroll
        for (int q = 0; q < 4; ++q) {
            float ga = fmaf(ft, g1f[q] - g0f[q], g0f[q]);
            float be = fmaf(ft, e1f[q] - e0f[q], e0f[q]);
            fz[q] = fmaf(ga, acc[kb * 4 + q], be);
        }
#pragma unroll
        for (int m = 0; m < 18; ++m) {
            const float* whr = Wh + m * 64 + kb * 4;
            float pm = pp[m];
            pm = fmaf(fz[0], whr[0], pm);
            pm = fmaf(fz[1], whr[1], pm);
            pm = fmaf(fz[2], whr[2], pm);
            pm = fmaf(fz[3], whr[3], pm);
            pp[m] = pm;
        }
    }

    float o[18];
    bool flag = false;
    {
        float l0 = pp[0], l1 = pp[6], l2 = pp[12];
        float mx = fmaxf(l0, fmaxf(l1, l2));
        float ex0 = __expf(l0 - mx), ex1 = __expf(l1 - mx), ex2 = __expf(l2 - mx);
        float inv = __fdividef(1.0f, ex0 + ex1 + ex2);
        o[0] = ex0 * inv; o[6] = ex1 * inv; o[12] = ex2 * inv;
#pragma unroll
        for (int kk = 0; kk < 3; ++kk) {
            o[kk * 6 + 1] = fmaxf(pp[kk * 6 + 1], 0.0f);
            float an = pp[kk * 6 + 2];
            float fl = floorf(an * (1.0f / TWO_PI_F));
            o[kk * 6 + 2] = an - fl * TWO_PI_F;
            float r = an - TWO_PI_F * rintf(an * (1.0f / TWO_PI_F));
            if (fabsf(r) < tau) flag = true;
            float v1 = fminf(fmaxf(pp[kk * 6 + 3], -10.0f), 10.0f);
            o[kk * 6 + 3] = __expf(v1);
            float v2 = fminf(fmaxf(pp[kk * 6 + 4], -10.0f), 10.0f);
            o[kk * 6 + 4] = __expf(v2);
            float e2 = __expf(2.0f * pp[kk * 6 + 5]);
            o[kk * 6 + 5] = 0.99f * __fdividef(e2 - 1.0f, e2 + 1.0f);
        }
    }

    float* og = out + (size_t)n * 18;
#pragma unroll
    for (int i = 0; i < 18; i += 2)
        *reinterpret_cast<float2*>(og + i) = make_float2(o[i], o[i + 1]);
    float* oc = out + (size_t)18 * NPTS + (size_t)n * 3;
    oc[0] = xf; oc[1] = yf; oc[2] = tf;

    if (flag) atomicOr(&bmp[n >> 5], 1u << (n & 31));
}

extern "C" void kernel_launch(void* const* d_in, const int* in_sizes, int n_in,
                              void* d_out, int out_size, void* d_ws, size_t ws_size,
                              hipStream_t stream) {
    const float* coords = (const float*)d_in[0];
    const float* grid   = (const float*)d_in[1];
    const float* W1  = (const float*)d_in[2];
    const float* b1  = (const float*)d_in[3];
    const float* W2  = (const float*)d_in[4];
    const float* b2  = (const float*)d_in[5];
    const float* Ws1 = (const float*)d_in[6];
    const float* bs1 = (const float*)d_in[7];
    const float* Ws2 = (const float*)d_in[8];
    const float* bs2 = (const float*)d_in[9];
    const float* Wf  = (const float*)d_in[10];
    const float* bf  = (const float*)d_in[11];
    const float* Wh  = (const float*)d_in[12];
    const float* bh  = (const float*)d_in[13];
    char* ws = (char*)d_ws;
    double* wd = (double*)ws;
    float* out = (float*)d_out;

    prep_k<<<32, 256, 0, stream>>>(W1, b1, W2, b2, Ws1, bs1, Ws2, bs2,
                                   Wf, bf, Wh, bh, ws);

    size_t need1024 = (size_t)GB_OFF + 1024ull * 512ull;
    size_t need4096 = (size_t)GB_OFF + 4096ull * 512ull;
    if (ws_size < need1024) {
        full_f64_fb<<<16384, 64, 0, stream>>>(coords, grid, wd, out);
        return;
    }

    float* W2T32 = (float*)(ws + W2T32_OFF);
    float* proj  = (float*)(ws + PROJ_OFF);
    unsigned* bmp = (unsigned*)(ws + BMP_OFF);
    unsigned* cnt = (unsigned*)(ws + CNT_OFF);
    float* gbt   = (float*)(ws + GB_OFF);

    const int nblk = (NPTS + 255) / 256;
    if (ws_size >= WS_SORT_MIN) {
        int bins = 4096; float tau = 5.0e-4f;
        unsigned* hist = (unsigned*)(ws + HIST_OFF);
        unsigned* part = (unsigned*)(ws + PART_OFF);
        float* w1xyp   = (float*)(ws + W1XY_OFF);
        short* bfh     = (short*)(ws + BFH_OFF);
        short* bfl     = (short*)(ws + BFL_OFF);
        float4* csort  = (float4*)(ws + CSORT_OFF);

        build_proj<<<2048, 256, 0, stream>>>(grid, wd, proj, bmp, hist, cnt);
        build_gb<<<1024, 256, 0, stream>>>(wd, gbt, bins);
        hist_k<<<nblk, 256, 0, stream>>>(coords, hist);
        scan1_k<<<NKEYS / 256, 256, 0, stream>>>(hist, part);
        scan2_k<<<1, 1024, 0, stream>>>(part);
        scan3_k<<<NKEYS / 256, 256, 0, stream>>>(hist, part);
        scatter_k<<<nblk, 256, 0, stream>>>(coords, hist, csort);
        main_mfma<<<NPTS / 64, 64, 0, stream>>>(
            csort, proj, gbt, bfh, bfl, w1xyp, b1, b2, Wh, bh,
            bins, tau, out, cnt, hist /* list reuses hist */, bmp);
        repair_list<<<8192, 64, 0, stream>>>(coords, grid, wd, Wh, bh,
                                             cnt, hist, out);
        repair_bmp<<<2048, 64, 0, stream>>>(coords, grid, wd, bmp, out);
    } else {
        int bins = (ws_size >= need4096) ? 4096 : 1024;
        float tau = (bins >= 4096) ? 1.5e-3f : 5.0e-3f;
        build_proj<<<2048, 256, 0, stream>>>(grid, wd, proj, bmp,
                                             (unsigned*)nullptr, cnt);
        build_gb<<<(bins + 3) / 4, 256, 0, stream>>>(wd, gbt, bins);
        main_unsorted<<<nblk, 256, 0, stream>>>(
            coords, W1, b1, b2, Wh, bh, W2T32, proj, gbt, bins, tau, out, bmp);
        repair_bmp<<<2048, 64, 0, stream>>>(coords, grid, wd, bmp, out);
    }
}

// Round 13
// 544.726 us; speedup vs baseline: 1.0299x; 1.0299x over previous
//
#include <hip/hip_runtime.h>
#include <math.h>

#define NPTS 1000000
#define NWORDS 31250            // NPTS/32 bitmap words
#define NKEYS 262144            // 4096 cells * 64 t-bins
#define LIST_CAP 262144
#define TWO_PI_D 6.283185307179586
#define TWO_PI_F 6.28318530717958647692f

// ---------------- f64 weight workspace (offsets in doubles) ----------------
#define OFF_W1   0        // 4352  row-major [128][34]
#define OFF_W1T  4352     // 4352  W1T[i*128+j] = W1[j*34+i]
#define OFF_W2T  8704     // 8192  W2T[j*64+k] = W2[k*128+j]
#define OFF_WS1  16896    // 128
#define OFF_BS1  17024    // 128
#define OFF_WS2T 17152    // 8192
#define OFF_BS2  25344    // 64
#define OFF_WFT  25408    // 8192  WfT[m*128+r] = Wf[r*64+m]
#define OFF_BF   33600    // 128
#define OFF_WHT  33728    // 1152  WhT[k*18+m] = Wh[m*64+k]
#define OFF_BH   34880    // 18
#define OFF_B1   34898    // 128
#define OFF_B2   35026    // 64
#define WD_DOUBLES 35090  // 280720 bytes

// ---------------- f32 / sort areas (byte offsets) ----------------
#define W2T32_OFF  280832                 // 8192 f32
#define PROJ_OFF   313600                 // 64*64*128 f32 = 2 MB
#define BMP_OFF    2410752                // 31250 u32 (area padded to 128KB)
#define CNT_OFF    2536192                // 1 u32, inside BMP pad
#define GB_OFF     2541824                // bins*128 f32 (4096 bins = 2MB)
#define HIST_OFF   4638976                // 262144 u32 = 1 MB (reused as repair list)
#define PART_OFF   5687552                // 1024 u32
#define W1XY_OFF   5691648                // 128 float2 = 1 KB
#define BFH_OFF    5692672                // 8192 short = 16 KB (B-frag hi)
#define BFL_OFF    5709056                // 8192 short = 16 KB (B-frag lo)
#define CSORT_OFF  5725440                // 1M float4 = 16 MB (16B aligned)
#define WS_SORT_MIN (CSORT_OFF + 16000000ull)

// fused setup kernel block ranges
#define SB_PROJ 2048
#define SB_GB   1024
#define SB_HIST 3907
#define SETUP_BLKS (SB_PROJ + SB_GB + SB_HIST)

typedef __attribute__((ext_vector_type(8))) short bf16x8;
typedef __attribute__((ext_vector_type(4))) float f32x4;

__device__ __forceinline__ short f2bf(float x) {      // RNE f32->bf16 (finite)
    unsigned u = __float_as_uint(x);
    unsigned r = (u + 0x7FFFu + ((u >> 16) & 1u)) >> 16;
    return (short)r;
}
__device__ __forceinline__ float bf2f(short s) {
    return __uint_as_float(((unsigned)(unsigned short)s) << 16);
}
__device__ __forceinline__ void st4(float* d, float4 v) {
    d[0] = v.x; d[1] = v.y; d[2] = v.z; d[3] = v.w;
}

__device__ __forceinline__ unsigned point_key(float xf, float yf, float tf)
{
    float xi = (xf + 1.0f) * 0.5f * 63.0f;
    float yi = (yf + 1.0f) * 0.5f * 63.0f;
    int x0 = (int)floorf(xi); x0 = x0 < 0 ? 0 : (x0 > 62 ? 62 : x0);
    int y0 = (int)floorf(yi); y0 = y0 < 0 ? 0 : (y0 > 62 ? 62 : y0);
    float u = (tf + 1.0f) * 32.0f;
    int tb = (int)u; tb = tb < 0 ? 0 : (tb > 63 ? 63 : tb);
    return ((unsigned)(y0 * 64 + x0) << 6) | (unsigned)tb;
}

// ============================================================
// prep: f64 weights (+transposes) + f32 W2T + w1xy pack + W2 B-frags
// + ALL zeroing (bmp/cnt always when zmode>=1; hist when zmode>=2)
// ============================================================
__global__ __launch_bounds__(256) void prep_k(
    const float* __restrict__ W1, const float* __restrict__ b1,
    const float* __restrict__ W2, const float* __restrict__ b2,
    const float* __restrict__ Ws1, const float* __restrict__ bs1,
    const float* __restrict__ Ws2, const float* __restrict__ bs2,
    const float* __restrict__ Wf, const float* __restrict__ bf,
    const float* __restrict__ Wh, const float* __restrict__ bh,
    char* __restrict__ ws, int zmode)
{
    double* wd = (double*)ws;
    float* w2t32 = (float*)(ws + W2T32_OFF);
    float2* w1xyp = (float2*)(ws + W1XY_OFF);
    short* bfh = (short*)(ws + BFH_OFF);
    short* bfl = (short*)(ws + BFL_OFF);
    int i = blockIdx.x * 256 + threadIdx.x;

    if (zmode >= 1) {
        unsigned* bmp = (unsigned*)(ws + BMP_OFF);
        for (int j = i; j < NWORDS; j += 32 * 256) bmp[j] = 0u;
        if (i == 0) *(unsigned*)(ws + CNT_OFF) = 0u;
    }
    if (zmode >= 2) {
        unsigned* hist = (unsigned*)(ws + HIST_OFF);
        for (int j = i; j < NKEYS; j += 32 * 256) hist[j] = 0u;
    }

    if (i < 4352) {
        wd[OFF_W1 + i] = (double)W1[i];
        int row = i >> 7, col = i & 127;           // W1T[row*128+col]
        wd[OFF_W1T + i] = (double)W1[col * 34 + row];
    }
    if (i < 8192) {
        int j = i >> 6, k = i & 63;
        float w2v = W2[k * 128 + j];
        wd[OFF_W2T + i] = (double)w2v;  w2t32[i] = w2v;
        wd[OFF_WS2T + i] = (double)Ws2[k * 128 + j];
        int m = i >> 7, r = i & 127;
        wd[OFF_WFT + i] = (double)Wf[r * 64 + m];
    }
    if (i < 8192) {   // MFMA B-fragments of W2: B[j][n] = W2[n*128+j], bf16 hi/lo
        int jj = i & 7, l = (i >> 3) & 63, f = i >> 9;
        int ks = f >> 2, nt = f & 3;
        int j = ks * 32 + ((l >> 4) << 3) + jj;
        int nn = nt * 16 + (l & 15);
        float v = W2[nn * 128 + j];
        short hi = f2bf(v);
        bfh[i] = hi;
        bfl[i] = f2bf(v - bf2f(hi));
    }
    if (i < 1152) {
        int m = i % 18, k = i / 18;
        wd[OFF_WHT + i] = (double)Wh[m * 64 + k];
    }
    if (i < 128) {
        wd[OFF_WS1 + i] = (double)Ws1[i];
        wd[OFF_BS1 + i] = (double)bs1[i];
        wd[OFF_BF  + i] = (double)bf[i];
        wd[OFF_B1  + i] = (double)b1[i];
        w1xyp[i] = make_float2(W1[i * 34], W1[i * 34 + 1]);
    }
    if (i < 64) {
        wd[OFF_BS2 + i] = (double)bs2[i];
        wd[OFF_B2  + i] = (double)b2[i];
    }
    if (i < 18) wd[OFF_BH + i] = (double)bh[i];
}

// ============================================================
// FUSED setup: proj table || gamma/beta table || hist
// (block-uniform role split; all three independent; zeroing done in prep_k)
// ============================================================
__global__ __launch_bounds__(256) void setup_k(
    const float* __restrict__ grid, const double* __restrict__ wd,
    float* __restrict__ proj, float* __restrict__ GB,
    const float* __restrict__ coords, unsigned* __restrict__ hist)
{
    __shared__ double sh[4 * 128];
    const int b = blockIdx.x;

    if (b < SB_PROJ) {
        // ---- proj[node*128+j] = sum_i W1[j][2+i]*grid[node][i] (f64) ----
        int idx = b * 256 + threadIdx.x;     // < 524288
        int j = idx & 127, node = idx >> 7;
        const double* W1T = wd + OFF_W1T;
        const float* g = grid + node * 32;
        double s0 = 0, s1 = 0, s2 = 0, s3 = 0;
#pragma unroll
        for (int i = 0; i < 32; i += 4) {
            s0 = fma((double)g[i + 0], W1T[(2 + i + 0) * 128 + j], s0);
            s1 = fma((double)g[i + 1], W1T[(2 + i + 1) * 128 + j], s1);
            s2 = fma((double)g[i + 2], W1T[(2 + i + 2) * 128 + j], s2);
            s3 = fma((double)g[i + 3], W1T[(2 + i + 3) * 128 + j], s3);
        }
        proj[idx] = (float)((s0 + s2) + (s1 + s3));
    } else if (b < SB_PROJ + SB_GB) {
        // ---- gamma/beta table, 4096 bins, one wave per bin (f64) ----
        int wid = threadIdx.x >> 6, lane = threadIdx.x & 63;
        double* buf = sh + wid * 128;
        int bin = (b - SB_PROJ) * 4 + wid;   // < 4096
        double t = -1.0 + 2.0 * (double)bin / 4095.0;

        buf[lane]      = sin(30.0 * fma(t, wd[OFF_WS1 + lane],      wd[OFF_BS1 + lane]));
        buf[lane + 64] = sin(30.0 * fma(t, wd[OFF_WS1 + 64 + lane], wd[OFF_BS1 + 64 + lane]));
        __threadfence_block();
        double a0 = wd[OFF_BS2 + lane], a1 = 0, a2 = 0, a3 = 0;
        const double* W = wd + OFF_WS2T;
#pragma unroll 2
        for (int j = 0; j < 128; j += 4) {
            a0 = fma(buf[j + 0], W[(j + 0) * 64 + lane], a0);
            a1 = fma(buf[j + 1], W[(j + 1) * 64 + lane], a1);
            a2 = fma(buf[j + 2], W[(j + 2) * 64 + lane], a2);
            a3 = fma(buf[j + 3], W[(j + 3) * 64 + lane], a3);
        }
        double ht = sin((a0 + a2) + (a1 + a3));
        __threadfence_block();
        buf[lane] = ht;
        __threadfence_block();
        double g0 = wd[OFF_BF + lane], g1 = 0, e0 = wd[OFF_BF + 64 + lane], e1 = 0;
        const double* WT = wd + OFF_WFT;
#pragma unroll 2
        for (int m = 0; m < 64; m += 2) {
            double h0 = buf[m], h1 = buf[m + 1];
            g0 = fma(h0, WT[(m + 0) * 128 + lane], g0);
            g1 = fma(h1, WT[(m + 1) * 128 + lane], g1);
            e0 = fma(h0, WT[(m + 0) * 128 + 64 + lane], e0);
            e1 = fma(h1, WT[(m + 1) * 128 + 64 + lane], e1);
        }
        GB[(size_t)bin * 128 + lane]      = (float)fma(0.1, tanh(g0 + g1), 1.0);
        GB[(size_t)bin * 128 + 64 + lane] = (float)tanh(e0 + e1);
    } else {
        // ---- hist ----
        int n = (b - SB_PROJ - SB_GB) * 256 + threadIdx.x;
        if (n < NPTS) {
            unsigned key = point_key(coords[3 * n], coords[3 * n + 1],
                                     coords[3 * n + 2]);
            atomicAdd(&hist[key], 1u);
        }
    }
}

// ============================================================
// standalone proj/gb kernels (small-ws fallback paths only)
// ============================================================
__global__ __launch_bounds__(256) void build_proj(
    const float* __restrict__ grid, const double* __restrict__ wd,
    float* __restrict__ proj)
{
    int idx = blockIdx.x * 256 + threadIdx.x;
    if (idx >= 64 * 64 * 128) return;
    int j = idx & 127, node = idx >> 7;
    const double* W1T = wd + OFF_W1T;
    const float* g = grid + node * 32;
    double s0 = 0, s1 = 0, s2 = 0, s3 = 0;
#pragma unroll
    for (int i = 0; i < 32; i += 4) {
        s0 = fma((double)g[i + 0], W1T[(2 + i + 0) * 128 + j], s0);
        s1 = fma((double)g[i + 1], W1T[(2 + i + 1) * 128 + j], s1);
        s2 = fma((double)g[i + 2], W1T[(2 + i + 2) * 128 + j], s2);
        s3 = fma((double)g[i + 3], W1T[(2 + i + 3) * 128 + j], s3);
    }
    proj[idx] = (float)((s0 + s2) + (s1 + s3));
}

__global__ __launch_bounds__(256) void build_gb(
    const double* __restrict__ wd, float* __restrict__ GB, int bins)
{
    __shared__ double sh[4 * 128];
    int wid = threadIdx.x >> 6, lane = threadIdx.x & 63;
    double* buf = sh + wid * 128;
    int bin = blockIdx.x * 4 + wid;
    if (bin >= bins) return;
    double t = -1.0 + 2.0 * (double)bin / (double)(bins - 1);

    buf[lane]      = sin(30.0 * fma(t, wd[OFF_WS1 + lane],      wd[OFF_BS1 + lane]));
    buf[lane + 64] = sin(30.0 * fma(t, wd[OFF_WS1 + 64 + lane], wd[OFF_BS1 + 64 + lane]));
    __threadfence_block();
    double a0 = wd[OFF_BS2 + lane], a1 = 0, a2 = 0, a3 = 0;
    const double* W = wd + OFF_WS2T;
#pragma unroll 2
    for (int j = 0; j < 128; j += 4) {
        a0 = fma(buf[j + 0], W[(j + 0) * 64 + lane], a0);
        a1 = fma(buf[j + 1], W[(j + 1) * 64 + lane], a1);
        a2 = fma(buf[j + 2], W[(j + 2) * 64 + lane], a2);
        a3 = fma(buf[j + 3], W[(j + 3) * 64 + lane], a3);
    }
    double ht = sin((a0 + a2) + (a1 + a3));
    __threadfence_block();
    buf[lane] = ht;
    __threadfence_block();
    double g0 = wd[OFF_BF + lane], g1 = 0, e0 = wd[OFF_BF + 64 + lane], e1 = 0;
    const double* WT = wd + OFF_WFT;
#pragma unroll 2
    for (int m = 0; m < 64; m += 2) {
        double h0 = buf[m], h1 = buf[m + 1];
        g0 = fma(h0, WT[(m + 0) * 128 + lane], g0);
        g1 = fma(h1, WT[(m + 1) * 128 + lane], g1);
        e0 = fma(h0, WT[(m + 0) * 128 + 64 + lane], e0);
        e1 = fma(h1, WT[(m + 1) * 128 + 64 + lane], e1);
    }
    GB[(size_t)bin * 128 + lane]      = (float)fma(0.1, tanh(g0 + g1), 1.0);
    GB[(size_t)bin * 128 + 64 + lane] = (float)tanh(e0 + e1);
}

// ============================================================
// scan machinery
// ============================================================
__global__ __launch_bounds__(256) void scan1_k(
    const unsigned* __restrict__ hist, unsigned* __restrict__ part)
{
    __shared__ unsigned s[256];
    int t = threadIdx.x;
    s[t] = hist[blockIdx.x * 256 + t];
    __syncthreads();
    for (int off = 128; off > 0; off >>= 1) {
        if (t < off) s[t] += s[t + off];
        __syncthreads();
    }
    if (t == 0) part[blockIdx.x] = s[0];
}

__global__ __launch_bounds__(1024) void scan2_k(unsigned* __restrict__ part)
{
    __shared__ unsigned s[1024];
    int t = threadIdx.x;
    unsigned orig = part[t];
    s[t] = orig;
    __syncthreads();
    for (int off = 1; off < 1024; off <<= 1) {
        unsigned tmp = (t >= off) ? s[t - off] : 0u;
        __syncthreads();
        s[t] += tmp;
        __syncthreads();
    }
    part[t] = s[t] - orig;        // exclusive prefix
}

__global__ __launch_bounds__(256) void scan3_k(
    unsigned* __restrict__ hist, const unsigned* __restrict__ part)
{
    __shared__ unsigned s[256];
    int t = threadIdx.x;
    int i = blockIdx.x * 256 + t;
    unsigned orig = hist[i];
    s[t] = orig;
    __syncthreads();
    for (int off = 1; off < 256; off <<= 1) {
        unsigned tmp = (t >= off) ? s[t - off] : 0u;
        __syncthreads();
        s[t] += tmp;
        __syncthreads();
    }
    hist[i] = s[t] - orig + part[blockIdx.x];   // global exclusive offset
}

__global__ __launch_bounds__(256) void scatter_k(
    const float* __restrict__ coords, unsigned* __restrict__ offs,
    float4* __restrict__ csort)
{
    int n = blockIdx.x * 256 + threadIdx.x;
    if (n >= NPTS) return;
    float xf = coords[3 * n], yf = coords[3 * n + 1], tf = coords[3 * n + 2];
    unsigned key = point_key(xf, yf, tf);
    unsigned pos = atomicAdd(&offs[key], 1u);
    csort[pos] = make_float4(xf, yf, tf, __int_as_float(n));
}

// ============================================================
// exact f64 wave-cooperative FULL point eval (overflow repair + fallback)
// ============================================================
__device__ __forceinline__ void eval_pt_wave(
    int n, int lane, double* buf,
    const float* __restrict__ coords, const float* __restrict__ grid,
    const double* __restrict__ wd, float* __restrict__ out, bool wrc)
{
    const float xf = coords[3 * n + 0];
    const float yf = coords[3 * n + 1];
    const float tf = coords[3 * n + 2];

    double xi = ((double)xf + 1.0) * 0.5 * 63.0;
    double yi = ((double)yf + 1.0) * 0.5 * 63.0;
    int x0 = (int)floor(xi); x0 = x0 < 0 ? 0 : (x0 > 62 ? 62 : x0);
    int y0 = (int)floor(yi); y0 = y0 < 0 ? 0 : (y0 > 62 ? 62 : y0);
    double dx = xi - (double)x0;
    double dy = yi - (double)y0;
    double w00 = (1.0 - dx) * (1.0 - dy);
    double w01 = (1.0 - dx) * dy;
    double w10 = dx * (1.0 - dy);
    double w11 = dx * dy;
    const float* f00 = grid + ((size_t)(y0 * 64 + x0)) * 32;

    if (lane < 32) {
        double v = (w00 * (double)f00[lane] + w01 * (double)f00[2048 + lane])
                 + (w10 * (double)f00[32 + lane] + w11 * (double)f00[2080 + lane]);
        buf[192 + 2 + lane] = v;
    } else if (lane == 32) buf[192 + 0] = (double)xf;
    else if (lane == 33)   buf[192 + 1] = (double)yf;
    __threadfence_block();

    double hlo = wd[OFF_B1 + lane], hhi = wd[OFF_B1 + 64 + lane];
    {
        const double* W = wd + OFF_W1T;
#pragma unroll 2
        for (int i = 0; i < 34; ++i) {
            double xv = buf[192 + i];
            hlo = fma(xv, W[i * 128 + lane], hlo);
            hhi = fma(xv, W[i * 128 + 64 + lane], hhi);
        }
    }
    buf[lane]      = fmax(hlo, 0.0);
    buf[64 + lane] = fmax(hhi, 0.0);
    __threadfence_block();

    double c0 = wd[OFF_B2 + lane], c1 = 0, c2 = 0, c3 = 0;
    {
        const double* W = wd + OFF_W2T;
#pragma unroll 2
        for (int j = 0; j < 128; j += 4) {
            c0 = fma(buf[j + 0], W[(j + 0) * 64 + lane], c0);
            c1 = fma(buf[j + 1], W[(j + 1) * 64 + lane], c1);
            c2 = fma(buf[j + 2], W[(j + 2) * 64 + lane], c2);
            c3 = fma(buf[j + 3], W[(j + 3) * 64 + lane], c3);
        }
    }
    double hxy = fmax((c0 + c2) + (c1 + c3), 0.0);
    __threadfence_block();

    double tt = (double)tf;
    buf[lane]      = sin(30.0 * fma(tt, wd[OFF_WS1 + lane],      wd[OFF_BS1 + lane]));
    buf[64 + lane] = sin(30.0 * fma(tt, wd[OFF_WS1 + 64 + lane], wd[OFF_BS1 + 64 + lane]));
    __threadfence_block();
    double a0 = wd[OFF_BS2 + lane], a1 = 0, a2 = 0, a3 = 0;
    {
        const double* W = wd + OFF_WS2T;
#pragma unroll 2
        for (int j = 0; j < 128; j += 4) {
            a0 = fma(buf[j + 0], W[(j + 0) * 64 + lane], a0);
            a1 = fma(buf[j + 1], W[(j + 1) * 64 + lane], a1);
            a2 = fma(buf[j + 2], W[(j + 2) * 64 + lane], a2);
            a3 = fma(buf[j + 3], W[(j + 3) * 64 + lane], a3);
        }
    }
    buf[128 + lane] = sin((a0 + a2) + (a1 + a3));
    __threadfence_block();

    double g0 = wd[OFF_BF + lane], g1 = 0, e0 = wd[OFF_BF + 64 + lane], e1 = 0;
    {
        const double* W = wd + OFF_WFT;
#pragma unroll 2
        for (int m = 0; m < 64; m += 2) {
            double h0 = buf[128 + m], h1 = buf[128 + m + 1];
            g0 = fma(h0, W[(m + 0) * 128 + lane], g0);
            g1 = fma(h1, W[(m + 1) * 128 + lane], g1);
            e0 = fma(h0, W[(m + 0) * 128 + 64 + lane], e0);
            e1 = fma(h1, W[(m + 1) * 128 + 64 + lane], e1);
        }
    }
    double fused = fma(fma(0.1, tanh(g0 + g1), 1.0), hxy, tanh(e0 + e1));
    __threadfence_block();
    buf[lane] = fused;
    __threadfence_block();

    if (lane < 18) {
        const double* W = wd + OFF_WHT;
        double p0 = wd[OFF_BH + lane], p1 = 0;
#pragma unroll 2
        for (int k = 0; k < 64; k += 2) {
            p0 = fma(buf[k + 0], W[(k + 0) * 18 + lane], p0);
            p1 = fma(buf[k + 1], W[(k + 1) * 18 + lane], p1);
        }
        buf[128 + lane] = p0 + p1;
    }
    __threadfence_block();

    if (lane < 18) {
        int m6 = lane % 6;
        double p = buf[128 + lane];
        float ov;
        if (m6 == 0) {
            double l0 = buf[128 + 0], l1 = buf[128 + 6], l2 = buf[128 + 12];
            double mx = fmax(l0, fmax(l1, l2));
            double s = exp(l0 - mx) + exp(l1 - mx) + exp(l2 - mx);
            ov = (float)(exp(p - mx) / s);
        } else if (m6 == 1) ov = (float)fmax(p, 0.0);
        else if (m6 == 2)   ov = (float)(p - floor(p / TWO_PI_D) * TWO_PI_D);
        else if (m6 == 5)   ov = (float)(0.99 * tanh(p));
        else { double v = fmin(fmax(p, -10.0), 10.0); ov = (float)exp(v); }
        out[(size_t)n * 18 + lane] = ov;
    }
    if (wrc && lane < 3)
        out[(size_t)18 * NPTS + (size_t)n * 3 + lane] = coords[3 * n + lane];
    __threadfence_block();
}

// ============================================================
// exact f64 ANGLE-ONLY eval: repairs out[n*18 + {2,8,14}] only
// ============================================================
__device__ __forceinline__ void eval_angle_wave(
    int n, int lane, double* buf,
    const float* __restrict__ coords, const float* __restrict__ grid,
    const double* __restrict__ wd, const float* __restrict__ Wh,
    const float* __restrict__ bh, float* __restrict__ out)
{
    const float xf = coords[3 * n + 0];
    const float yf = coords[3 * n + 1];
    const float tf = coords[3 * n + 2];

    double xi = ((double)xf + 1.0) * 0.5 * 63.0;
    double yi = ((double)yf + 1.0) * 0.5 * 63.0;
    int x0 = (int)floor(xi); x0 = x0 < 0 ? 0 : (x0 > 62 ? 62 : x0);
    int y0 = (int)floor(yi); y0 = y0 < 0 ? 0 : (y0 > 62 ? 62 : y0);
    double dx = xi - (double)x0;
    double dy = yi - (double)y0;
    double w00 = (1.0 - dx) * (1.0 - dy);
    double w01 = (1.0 - dx) * dy;
    double w10 = dx * (1.0 - dy);
    double w11 = dx * dy;
    const float* f00 = grid + ((size_t)(y0 * 64 + x0)) * 32;

    if (lane < 32) {
        double v = (w00 * (double)f00[lane] + w01 * (double)f00[2048 + lane])
                 + (w10 * (double)f00[32 + lane] + w11 * (double)f00[2080 + lane]);
        buf[192 + 2 + lane] = v;
    } else if (lane == 32) buf[192 + 0] = (double)xf;
    else if (lane == 33)   buf[192 + 1] = (double)yf;
    __threadfence_block();

    double hlo = wd[OFF_B1 + lane], hhi = wd[OFF_B1 + 64 + lane];
    {
        const double* W = wd + OFF_W1T;
#pragma unroll 2
        for (int i = 0; i < 34; ++i) {
            double xv = buf[192 + i];
            hlo = fma(xv, W[i * 128 + lane], hlo);
            hhi = fma(xv, W[i * 128 + 64 + lane], hhi);
        }
    }
    buf[lane]      = fmax(hlo, 0.0);
    buf[64 + lane] = fmax(hhi, 0.0);
    __threadfence_block();

    double c0 = wd[OFF_B2 + lane], c1 = 0, c2 = 0, c3 = 0;
    {
        const double* W = wd + OFF_W2T;
#pragma unroll 2
        for (int j = 0; j < 128; j += 4) {
            c0 = fma(buf[j + 0], W[(j + 0) * 64 + lane], c0);
            c1 = fma(buf[j + 1], W[(j + 1) * 64 + lane], c1);
            c2 = fma(buf[j + 2], W[(j + 2) * 64 + lane], c2);
            c3 = fma(buf[j + 3], W[(j + 3) * 64 + lane], c3);
        }
    }
    double hxy = fmax((c0 + c2) + (c1 + c3), 0.0);
    __threadfence_block();

    double tt = (double)tf;
    buf[lane]      = sin(30.0 * fma(tt, wd[OFF_WS1 + lane],      wd[OFF_BS1 + lane]));
    buf[64 + lane] = sin(30.0 * fma(tt, wd[OFF_WS1 + 64 + lane], wd[OFF_BS1 + 64 + lane]));
    __threadfence_block();
    double a0 = wd[OFF_BS2 + lane], a1 = 0, a2 = 0, a3 = 0;
    {
        const double* W = wd + OFF_WS2T;
#pragma unroll 2
        for (int j = 0; j < 128; j += 4) {
            a0 = fma(buf[j + 0], W[(j + 0) * 64 + lane], a0);
            a1 = fma(buf[j + 1], W[(j + 1) * 64 + lane], a1);
            a2 = fma(buf[j + 2], W[(j + 2) * 64 + lane], a2);
            a3 = fma(buf[j + 3], W[(j + 3) * 64 + lane], a3);
        }
    }
    buf[128 + lane] = sin((a0 + a2) + (a1 + a3));
    __threadfence_block();

    double g0 = wd[OFF_BF + lane], g1 = 0, e0 = wd[OFF_BF + 64 + lane], e1 = 0;
    {
        const double* W = wd + OFF_WFT;
#pragma unroll 2
        for (int m = 0; m < 64; m += 2) {
            double h0 = buf[128 + m], h1 = buf[128 + m + 1];
            g0 = fma(h0, W[(m + 0) * 128 + lane], g0);
            g1 = fma(h1, W[(m + 1) * 128 + lane], g1);
            e0 = fma(h0, W[(m + 0) * 128 + 64 + lane], e0);
            e1 = fma(h1, W[(m + 1) * 128 + 64 + lane], e1);
        }
    }
    double fused = fma(fma(0.1, tanh(g0 + g1), 1.0), hxy, tanh(e0 + e1));

    // head rows 2, 8, 14 only: per-lane product + butterfly reduce (f64 exact)
    double p2  = fused * (double)Wh[2 * 64 + lane];
    double p8  = fused * (double)Wh[8 * 64 + lane];
    double p14 = fused * (double)Wh[14 * 64 + lane];
#pragma unroll
    for (int off = 32; off > 0; off >>= 1) {
        p2  += __shfl_xor(p2, off);
        p8  += __shfl_xor(p8, off);
        p14 += __shfl_xor(p14, off);
    }
    if (lane == 0) {
        double q2  = p2  + (double)bh[2];
        double q8  = p8  + (double)bh[8];
        double q14 = p14 + (double)bh[14];
        out[(size_t)n * 18 + 2]  = (float)(q2  - floor(q2  / TWO_PI_D) * TWO_PI_D);
        out[(size_t)n * 18 + 8]  = (float)(q8  - floor(q8  / TWO_PI_D) * TWO_PI_D);
        out[(size_t)n * 18 + 14] = (float)(q14 - floor(q14 / TWO_PI_D) * TWO_PI_D);
    }
    __threadfence_block();
}

// ============================================================
// repair: load-balanced list walk, 1-wave blocks (angle-only)
// ============================================================
__global__ __launch_bounds__(64) void repair_list(
    const float* __restrict__ coords, const float* __restrict__ grid,
    const double* __restrict__ wd, const float* __restrict__ Wh,
    const float* __restrict__ bh, const unsigned* __restrict__ cnt,
    const unsigned* __restrict__ list, float* __restrict__ out)
{
    __shared__ double buf[232];
    int lane = threadIdx.x;
    unsigned total = *cnt;
    if (total > LIST_CAP) total = LIST_CAP;
    for (unsigned i = blockIdx.x; i < total; i += gridDim.x)
        eval_angle_wave((int)list[i], lane, buf, coords, grid, wd, Wh, bh, out);
}

// overflow / fallback: bitmap scan, full eval, 1-wave blocks
__global__ __launch_bounds__(64) void repair_bmp(
    const float* __restrict__ coords, const float* __restrict__ grid,
    const double* __restrict__ wd, const unsigned* __restrict__ bmp,
    float* __restrict__ out)
{
    __shared__ double buf[232];
    int lane = threadIdx.x;
    for (unsigned w = blockIdx.x; w < NWORDS; w += gridDim.x) {
        unsigned word = bmp[w];
        while (word) {
            unsigned b = (unsigned)__builtin_ctz(word);
            word &= word - 1;
            eval_pt_wave((int)(w * 32 + b), lane, buf, coords, grid, wd, out, false);
        }
    }
}

__global__ __launch_bounds__(64) void full_f64_fb(
    const float* __restrict__ coords, const float* __restrict__ grid,
    const double* __restrict__ wd, float* __restrict__ out)
{
    __shared__ double buf[232];
    int lane = threadIdx.x;
    for (unsigned n = blockIdx.x; n < NPTS; n += gridDim.x)
        eval_pt_wave((int)n, lane, buf, coords, grid, wd, out, true);
}

// ============================================================
// MFMA main: 1 wave = 1 block = 64 sorted points (R11 baseline body)
// ============================================================
__global__ __launch_bounds__(64) void main_mfma(
    const float4* __restrict__ csort,
    const float* __restrict__ proj, const float* __restrict__ GB,
    const short* __restrict__ bfH, const short* __restrict__ bfL,
    const float* __restrict__ w1xy, const float* __restrict__ b1,
    const float* __restrict__ b2,
    const float* __restrict__ Wh, const float* __restrict__ bh,
    int bins, float tau, float* __restrict__ out,
    unsigned* __restrict__ cnt, unsigned* __restrict__ list,
    unsigned* __restrict__ bmp)
{
    __shared__ float wl[2048];          // 8 KB, private to this single-wave block
    const int lane = threadIdx.x;
    const int wavebase = blockIdx.x * 64;

    f32x4 acc[4][4];
#pragma unroll
    for (int a = 0; a < 4; ++a)
#pragma unroll
        for (int b = 0; b < 4; ++b) acc[a][b] = (f32x4){0.f, 0.f, 0.f, 0.f};

    // per-thread point + bilinear params
    float4 myc = csort[wavebase + lane];
    float w00, w01, w10, w11; int node;
    {
        float xi = (myc.x + 1.0f) * 0.5f * 63.0f;
        float yi = (myc.y + 1.0f) * 0.5f * 63.0f;
        int x0 = (int)floorf(xi); x0 = x0 < 0 ? 0 : (x0 > 62 ? 62 : x0);
        int y0 = (int)floorf(yi); y0 = y0 < 0 ? 0 : (y0 > 62 ? 62 : y0);
        float dx = xi - (float)x0;
        float dy = yi - (float)y0;
        w00 = (1.0f - dx) * (1.0f - dy);
        w01 = (1.0f - dx) * dy;
        w10 = dx * (1.0f - dy);
        w11 = dx * dy;
        node = y0 * 64 + x0;
    }
    // distribute tile-row params via shuffles (A-frag row = lane&15 of tile mt)
    float px[4], py[4], pw00[4], pw01[4], pw10[4], pw11[4];
    int pnode[4];
#pragma unroll
    for (int mt = 0; mt < 4; ++mt) {
        int src = mt * 16 + (lane & 15);
        px[mt]   = __shfl(myc.x, src);
        py[mt]   = __shfl(myc.y, src);
        pw00[mt] = __shfl(w00, src);
        pw01[mt] = __shfl(w01, src);
        pw10[mt] = __shfl(w10, src);
        pw11[mt] = __shfl(w11, src);
        pnode[mt] = __shfl(node, src);
    }

#pragma unroll 1
    for (int ks = 0; ks < 4; ++ks) {
        const int dbase = ks * 32 + ((lane >> 4) << 3);
        bf16x8 bHf[4], bLf[4];
#pragma unroll
        for (int nt = 0; nt < 4; ++nt) {
            int fi = ((ks * 4 + nt) * 64 + lane) * 8;
            bHf[nt] = *(const bf16x8*)(bfH + fi);
            bLf[nt] = *(const bf16x8*)(bfL + fi);
        }
        float b1r[8];
        st4(b1r,     *(const float4*)(b1 + dbase));
        st4(b1r + 4, *(const float4*)(b1 + dbase + 4));
        float wvr[16];                         // (x,y) pairs for 8 dims
        {
            const float4* wxy = (const float4*)w1xy + (dbase >> 1);
            st4(wvr,      wxy[0]);
            st4(wvr + 4,  wxy[1]);
            st4(wvr + 8,  wxy[2]);
            st4(wvr + 12, wxy[3]);
        }
#pragma unroll
        for (int mt = 0; mt < 4; ++mt) {
            const float* pj = proj + pnode[mt] * 128 + dbase;
            float q00[8], q10[8], q01[8], q11[8];
            st4(q00,     *(const float4*)(pj));
            st4(q00 + 4, *(const float4*)(pj + 4));
            st4(q10,     *(const float4*)(pj + 128));
            st4(q10 + 4, *(const float4*)(pj + 132));
            st4(q01,     *(const float4*)(pj + 8192));
            st4(q01 + 4, *(const float4*)(pj + 8196));
            st4(q11,     *(const float4*)(pj + 8320));
            st4(q11 + 4, *(const float4*)(pj + 8324));
            bf16x8 ah, al;
            float xx = px[mt], yy = py[mt];
            float a00 = pw00[mt], a01 = pw01[mt], a10 = pw10[mt], a11 = pw11[mt];
#pragma unroll
            for (int jj = 0; jj < 8; ++jj) {
                float h = b1r[jj];
                h = fmaf(xx, wvr[jj * 2], h);
                h = fmaf(yy, wvr[jj * 2 + 1], h);
                h = fmaf(a00, q00[jj], h);
                h = fmaf(a01, q01[jj], h);
                h = fmaf(a10, q10[jj], h);
                h = fmaf(a11, q11[jj], h);
                h = fmaxf(h, 0.0f);
                short hi = f2bf(h);
                ah[jj] = hi;
                al[jj] = f2bf(h - bf2f(hi));
            }
#pragma unroll
            for (int nt = 0; nt < 4; ++nt) {
                acc[mt][nt] = __builtin_amdgcn_mfma_f32_16x16x32_bf16(ah, bHf[nt], acc[mt][nt], 0, 0, 0);
                acc[mt][nt] = __builtin_amdgcn_mfma_f32_16x16x32_bf16(ah, bLf[nt], acc[mt][nt], 0, 0, 0);
                acc[mt][nt] = __builtin_amdgcn_mfma_f32_16x16x32_bf16(al, bHf[nt], acc[mt][nt], 0, 0, 0);
            }
        }
    }

    // ---- phase 2: LDS transpose (swizzled) + FiLM + head, thread = point ----
    float pp[18];
    int ib, n_out;
    float ft;
    {
        float u = (myc.z + 1.0f) * 0.5f * (float)(bins - 1);
        ib = (int)u; ib = ib < 0 ? 0 : (ib > bins - 2 ? bins - 2 : ib);
        ft = u - (float)ib;
        n_out = __float_as_int(myc.w);
#pragma unroll
        for (int m = 0; m < 18; ++m) pp[m] = bh[m];
    }
    const int rbase = ((lane >> 4) << 2);
#pragma unroll
    for (int half = 0; half < 2; ++half) {
#pragma unroll
        for (int nt2 = 0; nt2 < 2; ++nt2) {
            int nt = half * 2 + nt2;
            int kl = nt2 * 16 + (lane & 15);
#pragma unroll
            for (int mt = 0; mt < 4; ++mt)
#pragma unroll
                for (int r = 0; r < 4; ++r) {
                    int pt = mt * 16 + rbase + r;
                    wl[kl * 64 + ((pt + kl) & 63)] = acc[mt][nt][r];
                }
        }
        __syncthreads();
        {
            const float* GAg = GB + (size_t)ib * 128 + half * 32;
            const float* GAe = GAg + 64;
            const float* GBg = GB + (size_t)(ib + 1) * 128 + half * 32;
            const float* GBe = GBg + 64;
#pragma unroll
            for (int c = 0; c < 8; ++c) {
                float g0r[4], g1r[4], e0r[4], e1r[4];
                st4(g0r, *(const float4*)(GAg + c * 4));
                st4(g1r, *(const float4*)(GBg + c * 4));
                st4(e0r, *(const float4*)(GAe + c * 4));
                st4(e1r, *(const float4*)(GBe + c * 4));
#pragma unroll
                for (int q = 0; q < 4; ++q) {
                    int kl = c * 4 + q, k = half * 32 + kl;
                    float v = wl[kl * 64 + ((lane + kl) & 63)];
                    float a = fmaxf(v + b2[k], 0.0f);
                    float ga = fmaf(ft, g1r[q] - g0r[q], g0r[q]);
                    float be = fmaf(ft, e1r[q] - e0r[q], e0r[q]);
                    float fz = fmaf(ga, a, be);
#pragma unroll
                    for (int m = 0; m < 18; ++m)
                        pp[m] = fmaf(fz, Wh[m * 64 + k], pp[m]);
                }
            }
        }
        __syncthreads();
    }

    float o[18];
    bool flag = false;
    {
        float l0 = pp[0], l1 = pp[6], l2 = pp[12];
        float mx = fmaxf(l0, fmaxf(l1, l2));
        float ex0 = __expf(l0 - mx), ex1 = __expf(l1 - mx), ex2 = __expf(l2 - mx);
        float inv = __fdividef(1.0f, ex0 + ex1 + ex2);
        o[0] = ex0 * inv; o[6] = ex1 * inv; o[12] = ex2 * inv;
#pragma unroll
        for (int kk = 0; kk < 3; ++kk) {
            o[kk * 6 + 1] = fmaxf(pp[kk * 6 + 1], 0.0f);
            float an = pp[kk * 6 + 2];
            float fl = floorf(an * (1.0f / TWO_PI_F));
            o[kk * 6 + 2] = an - fl * TWO_PI_F;
            float r = an - TWO_PI_F * rintf(an * (1.0f / TWO_PI_F));
            if (fabsf(r) < tau) flag = true;
            float v1 = fminf(fmaxf(pp[kk * 6 + 3], -10.0f), 10.0f);
            o[kk * 6 + 3] = __expf(v1);
            float v2 = fminf(fmaxf(pp[kk * 6 + 4], -10.0f), 10.0f);
            o[kk * 6 + 4] = __expf(v2);
            float e2 = __expf(2.0f * pp[kk * 6 + 5]);
            o[kk * 6 + 5] = 0.99f * __fdividef(e2 - 1.0f, e2 + 1.0f);
        }
    }

    float* og = out + (size_t)n_out * 18;
#pragma unroll
    for (int i = 0; i < 18; i += 2)
        *reinterpret_cast<float2*>(og + i) = make_float2(o[i], o[i + 1]);
    float* oc = out + (size_t)18 * NPTS + (size_t)n_out * 3;
    oc[0] = myc.x; oc[1] = myc.y; oc[2] = myc.z;

    if (flag) {
        unsigned idx = atomicAdd(cnt, 1u);
        if (idx < LIST_CAP) list[idx] = (unsigned)n_out;
        else atomicOr(&bmp[n_out >> 5], 1u << (n_out & 31));
    }
}

// ============================================================
// fast f32 point body (fallback unsorted main only; bitmap flags)
// ============================================================
__global__ __launch_bounds__(256) void main_unsorted(
    const float* __restrict__ coords,
    const float* __restrict__ W1, const float* __restrict__ b1,
    const float* __restrict__ b2,
    const float* __restrict__ Wh, const float* __restrict__ bh,
    const float* __restrict__ W2T,
    const float* __restrict__ PROJ, const float* __restrict__ GB,
    int bins, float tau,
    float* __restrict__ out, unsigned* __restrict__ bmp)
{
    int n = blockIdx.x * 256 + threadIdx.x;
    if (n >= NPTS) return;
    float xf = coords[3 * n], yf = coords[3 * n + 1], tf = coords[3 * n + 2];

    float xi = (xf + 1.0f) * 0.5f * 63.0f;
    float yi = (yf + 1.0f) * 0.5f * 63.0f;
    int x0 = (int)floorf(xi); x0 = x0 < 0 ? 0 : (x0 > 62 ? 62 : x0);
    int y0 = (int)floorf(yi); y0 = y0 < 0 ? 0 : (y0 > 62 ? 62 : y0);
    float dx = xi - (float)x0;
    float dy = yi - (float)y0;
    float w00 = (1.0f - dx) * (1.0f - dy);
    float w01 = (1.0f - dx) * dy;
    float w10 = dx * (1.0f - dy);
    float w11 = dx * dy;
    int node = y0 * 64 + x0;

    float u = (tf + 1.0f) * 0.5f * (float)(bins - 1);
    int ib = (int)u; ib = ib < 0 ? 0 : (ib > bins - 2 ? bins - 2 : ib);
    float ft = u - (float)ib;

    const float4* P00 = (const float4*)(PROJ + (size_t)node * 128);
    const float4* P10 = P00 + 32;
    const float4* P01 = P00 + 2048;
    const float4* P11 = P01 + 32;

    float acc[64];
#pragma unroll
    for (int k = 0; k < 64; ++k) acc[k] = b2[k];

#pragma unroll 1
    for (int jb = 0; jb < 32; ++jb) {
        float4 a00 = P00[jb], a01 = P01[jb], a10 = P10[jb], a11 = P11[jb];
        const float* a00f = (const float*)&a00;
        const float* a01f = (const float*)&a01;
        const float* a10f = (const float*)&a10;
        const float* a11f = (const float*)&a11;
        const float* w1b = W1 + jb * 136;
#pragma unroll
        for (int q = 0; q < 4; ++q) {
            float hq = b1[jb * 4 + q];
            hq = fmaf(xf, w1b[q * 34 + 0], hq);
            hq = fmaf(yf, w1b[q * 34 + 1], hq);
            hq = fmaf(w00, a00f[q], hq);
            hq = fmaf(w01, a01f[q], hq);
            hq = fmaf(w10, a10f[q], hq);
            hq = fmaf(w11, a11f[q], hq);
            hq = fmaxf(hq, 0.0f);
            const float* w2c = W2T + (jb * 4 + q) * 64;
#pragma unroll
            for (int k = 0; k < 64; ++k) acc[k] = fmaf(hq, w2c[k], acc[k]);
        }
    }
#pragma unroll
    for (int k = 0; k < 64; ++k) acc[k] = fmaxf(acc[k], 0.0f);

    float pp[18];
#pragma unroll
    for (int m = 0; m < 18; ++m) pp[m] = bh[m];

    const float4* GA = (const float4*)(GB + (size_t)ib * 128);
    const float4* GBn = (const float4*)(GB + (size_t)(ib + 1) * 128);
#pragma unroll
    for (int kb = 0; kb < 16; ++kb) {
        float4 g0 = GA[kb], g1 = GBn[kb], e0 = GA[16 + kb], e1 = GBn[16 + kb];
        const float* g0f = (const float*)&g0;
        const float* g1f = (const float*)&g1;
        const float* e0f = (const float*)&e0;
        const float* e1f = (const float*)&e1;
        float fz[4];
#pragma unroll
        for (int q = 0; q < 4; ++q) {
            float ga = fmaf(ft, g1f[q] - g0f[q], g0f[q]);
            float be = fmaf(ft, e1f[q] - e0f[q], e0f[q]);
            fz[q] = fmaf(ga, acc[kb * 4 + q], be);
        }
#pragma unroll
        for (int m = 0; m < 18; ++m) {
            const float* whr = Wh + m * 64 + kb * 4;
            float pm = pp[m];
            pm = fmaf(fz[0], whr[0], pm);
            pm = fmaf(fz[1], whr[1], pm);
            pm = fmaf(fz[2], whr[2], pm);
            pm = fmaf(fz[3], whr[3], pm);
            pp[m] = pm;
        }
    }

    float o[18];
    bool flag = false;
    {
        float l0 = pp[0], l1 = pp[6], l2 = pp[12];
        float mx = fmaxf(l0, fmaxf(l1, l2));
        float ex0 = __expf(l0 - mx), ex1 = __expf(l1 - mx), ex2 = __expf(l2 - mx);
        float inv = __fdividef(1.0f, ex0 + ex1 + ex2);
        o[0] = ex0 * inv; o[6] = ex1 * inv; o[12] = ex2 * inv;
#pragma unroll
        for (int kk = 0; kk < 3; ++kk) {
            o[kk * 6 + 1] = fmaxf(pp[kk * 6 + 1], 0.0f);
            float an = pp[kk * 6 + 2];
            float fl = floorf(an * (1.0f / TWO_PI_F));
            o[kk * 6 + 2] = an - fl * TWO_PI_F;
            float r = an - TWO_PI_F * rintf(an * (1.0f / TWO_PI_F));
            if (fabsf(r) < tau) flag = true;
            float v1 = fminf(fmaxf(pp[kk * 6 + 3], -10.0f), 10.0f);
            o[kk * 6 + 3] = __expf(v1);
            float v2 = fminf(fmaxf(pp[kk * 6 + 4], -10.0f), 10.0f);
            o[kk * 6 + 4] = __expf(v2);
            float e2 = __expf(2.0f * pp[kk * 6 + 5]);
            o[kk * 6 + 5] = 0.99f * __fdividef(e2 - 1.0f, e2 + 1.0f);
        }
    }

    float* og = out + (size_t)n * 18;
#pragma unroll
    for (int i = 0; i < 18; i += 2)
        *reinterpret_cast<float2*>(og + i) = make_float2(o[i], o[i + 1]);
    float* oc = out + (size_t)18 * NPTS + (size_t)n * 3;
    oc[0] = xf; oc[1] = yf; oc[2] = tf;

    if (flag) atomicOr(&bmp[n >> 5], 1u << (n & 31));
}

extern "C" void kernel_launch(void* const* d_in, const int* in_sizes, int n_in,
                              void* d_out, int out_size, void* d_ws, size_t ws_size,
                              hipStream_t stream) {
    const float* coords = (const float*)d_in[0];
    const float* grid   = (const float*)d_in[1];
    const float* W1  = (const float*)d_in[2];
    const float* b1  = (const float*)d_in[3];
    const float* W2  = (const float*)d_in[4];
    const float* b2  = (const float*)d_in[5];
    const float* Ws1 = (const float*)d_in[6];
    const float* bs1 = (const float*)d_in[7];
    const float* Ws2 = (const float*)d_in[8];
    const float* bs2 = (const float*)d_in[9];
    const float* Wf  = (const float*)d_in[10];
    const float* bf  = (const float*)d_in[11];
    const float* Wh  = (const float*)d_in[12];
    const float* bh  = (const float*)d_in[13];
    char* ws = (char*)d_ws;
    double* wd = (double*)ws;
    float* out = (float*)d_out;

    size_t need1024 = (size_t)GB_OFF + 1024ull * 512ull;
    size_t need4096 = (size_t)GB_OFF + 4096ull * 512ull;

    if (ws_size < need1024) {
        prep_k<<<32, 256, 0, stream>>>(W1, b1, W2, b2, Ws1, bs1, Ws2, bs2,
                                       Wf, bf, Wh, bh, ws, 0);
        full_f64_fb<<<16384, 64, 0, stream>>>(coords, grid, wd, out);
        return;
    }

    float* W2T32 = (float*)(ws + W2T32_OFF);
    float* proj  = (float*)(ws + PROJ_OFF);
    unsigned* bmp = (unsigned*)(ws + BMP_OFF);
    unsigned* cnt = (unsigned*)(ws + CNT_OFF);
    float* gbt   = (float*)(ws + GB_OFF);

    const int nblk = (NPTS + 255) / 256;
    if (ws_size >= WS_SORT_MIN) {
        int bins = 4096; float tau = 5.0e-4f;
        unsigned* hist = (unsigned*)(ws + HIST_OFF);
        unsigned* part = (unsigned*)(ws + PART_OFF);
        float* w1xyp   = (float*)(ws + W1XY_OFF);
        short* bfh     = (short*)(ws + BFH_OFF);
        short* bfl     = (short*)(ws + BFL_OFF);
        float4* csort  = (float4*)(ws + CSORT_OFF);

        prep_k<<<32, 256, 0, stream>>>(W1, b1, W2, b2, Ws1, bs1, Ws2, bs2,
                                       Wf, bf, Wh, bh, ws, 2);
        setup_k<<<SETUP_BLKS, 256, 0, stream>>>(grid, wd, proj, gbt,
                                                coords, hist);
        scan1_k<<<NKEYS / 256, 256, 0, stream>>>(hist, part);
        scan2_k<<<1, 1024, 0, stream>>>(part);
        scan3_k<<<NKEYS / 256, 256, 0, stream>>>(hist, part);
        scatter_k<<<nblk, 256, 0, stream>>>(coords, hist, csort);
        main_mfma<<<NPTS / 64, 64, 0, stream>>>(
            csort, proj, gbt, bfh, bfl, w1xyp, b1, b2, Wh, bh,
            bins, tau, out, cnt, hist /* list reuses hist */, bmp);
        repair_list<<<4096, 64, 0, stream>>>(coords, grid, wd, Wh, bh,
                                             cnt, hist, out);
        repair_bmp<<<2048, 64, 0, stream>>>(coords, grid, wd, bmp, out);
    } else {
        int bins = (ws_size >= need4096) ? 4096 : 1024;
        float tau = (bins >= 4096) ? 1.5e-3f : 5.0e-3f;
        prep_k<<<32, 256, 0, stream>>>(W1, b1, W2, b2, Ws1, bs1, Ws2, bs2,
                                       Wf, bf, Wh, bh, ws, 1);
        build_proj<<<2048, 256, 0, stream>>>(grid, wd, proj);
        build_gb<<<(bins + 3) / 4, 256, 0, stream>>>(wd, gbt, bins);
        main_unsorted<<<nblk, 256, 0, stream>>>(
            coords, W1, b1, b2, Wh, bh, W2T32, proj, gbt, bins, tau, out, bmp);
        repair_bmp<<<2048, 64, 0, stream>>>(coords, grid, wd, bmp, out);
    }
}